// Round 12
// baseline (66.640 us; speedup 1.0000x reference)
//
#include <hip/hip_runtime.h>
#include <hip/hip_fp16.h>

#define T_DIM   1500
#define ROW_F   32000
#define V4      8000               // float4 per row
#define HALF_F4 4000               // float4 per half-row
#define START_T 9                  // max(U-1,1), U=10
#define NB      16384              // N * ctc_beam
#define BLOCK   512
#define CPT     32                 // NB/BLOCK
#define NPAIR   16                 // CPT/2, packed candidate pairs
#define NJH     8                  // float4 per thread per half (7 full + tail)
#define TAILH   416                // 4000 - 7*512
#define ROWS    3                  // 500*3 = 1500 exactly
#define NCHUNK  500
#define NEGBIG  -3.0e38f
#define EOS_ID  1
#define LN2     0.69314718055994531f
#define L2E     1.44269504088896341f

#if __has_builtin(__builtin_amdgcn_exp2f)
__device__ __forceinline__ float fexp2(float x) { return __builtin_amdgcn_exp2f(x); }
#else
__device__ __forceinline__ float fexp2(float x) { return __expf(x * LN2); }
#endif
#if __has_builtin(__builtin_amdgcn_logf)
__device__ __forceinline__ float flog2(float x) { return __builtin_amdgcn_logf(x); }
#else
__device__ __forceinline__ float flog2(float x) { return __logf(x) * L2E; }
#endif

#define WG_BARRIER() do { \
  asm volatile("s_waitcnt lgkmcnt(0)" ::: "memory"); \
  __builtin_amdgcn_s_barrier(); \
  asm volatile("" ::: "memory"); \
} while (0)

struct alignas(8) H4 { __half2 a, b; };

// K1: 500 blocks x 3 rows, TWO independent blocks per CU (the new axis).
// LDS = 64KB single fp16-px row + red -> 2 blocks co-resident; VGPR ~100
// under the 128 cap of __launch_bounds__(512,2) -> no spill (half-row
// register staging va[8] = 32 VGPRs). Within a block: STAGE half0 (issue
// half1 loads) -> STAGE half1 (issue next row half0) -> bar -> GATHER ->
// bar. A block's HBM stalls are covered by the sibling block's stream.
__global__ __launch_bounds__(BLOCK, 2)
void ctc_k1(const float* __restrict__ P, const int* __restrict__ cidx,
            float* __restrict__ Lws, float* __restrict__ Sblank)
{
  __shared__ __align__(16) __half A[ROW_F];   // fp16 px row (64000 B)
  __shared__ float red[12];                   // 8 wave sums + blank logit
  const int tid = threadIdx.x;
  const int q   = blockIdx.x;
  const int t0  = q * ROWS;

  // candidate indices packed as two u16 LDS byte offsets per VGPR (c*2<64000)
  unsigned cidp[NPAIR];
  float s[CPT];
#pragma unroll
  for (int j = 0; j < NPAIR; ++j) {
    unsigned c0 = (unsigned)cidx[(2*j  )*BLOCK + tid] * 2u;
    unsigned c1 = (unsigned)cidx[(2*j+1)*BLOCK + tid] * 2u;
    cidp[j] = c0 | (c1 << 16);
    s[2*j] = 0.f; s[2*j+1] = 0.f;
  }

  const float4* __restrict__ P4 = (const float4*)P;
  const bool tailv = (tid < TAILH);

  float4 va[NJH];
  float  psum   = 0.f;
  float  blankv = 0.f;

  auto LOADH = [&](int t, int h) {
    const float4* rp = P4 + (long)t * V4 + h * HALF_F4;
#pragma unroll
    for (int j = 0; j < 7; ++j) va[j] = rp[j*BLOCK + tid];
    if (tailv) va[7] = rp[7*BLOCK + tid];
  };

  // px = exp2(x*log2e); f32 half-row sum into psum; fp16 px -> A.
  // Thread tid=415, h=1, j=7 owns f4 7999 -> elem 31999 (blank logit).
  auto STAGEH = [&](int h) {
    H4* rw = (H4*)A + h * HALF_F4;
#pragma unroll
    for (int j = 0; j < NJH; ++j) {
      if (j == 7 && !tailv) break;
      float p0 = fexp2(va[j].x * L2E);
      float p1 = fexp2(va[j].y * L2E);
      float p2 = fexp2(va[j].z * L2E);
      float p3 = fexp2(va[j].w * L2E);
      psum += (p0 + p1) + (p2 + p3);
      H4 hh; hh.a = __floats2half2_rn(p0, p1); hh.b = __floats2half2_rn(p2, p3);
      rw[j*BLOCK + tid] = hh;
      if (h == 1 && j == 7 && tid == TAILH - 1) blankv = va[7].w * L2E;
    }
  };

  float Blocal2 = 0.f;   // chunk-local blank prefix, log2 units
  auto GATHER = [&](int t) {
    float sum = red[0];
#pragma unroll
    for (int w = 1; w < 8; ++w) sum += red[w];
    const float lse2 = flog2(sum);
    if (t >= START_T) {
      const float sc = fexp2(Blocal2 - lse2);   // wave-uniform; no underflow in-chunk
      const char* rb = (const char*)A;
#pragma unroll
      for (int j = 0; j < NPAIR; ++j) {
        unsigned pk = cidp[j];
        float p0 = __half2float(*(const __half*)(rb + (pk & 0xffffu)));
        float p1 = __half2float(*(const __half*)(rb + (pk >> 16)));
        s[2*j]   = fmaf(sc, p0, s[2*j]);
        s[2*j+1] = fmaf(sc, p1, s[2*j+1]);
      }
    }
    Blocal2 += red[8] - lse2;
  };

  // prologue
  LOADH(t0, 0);

  for (int r = 0; r < ROWS; ++r) {
    const int t = t0 + r;
    psum = 0.f;
    STAGEH(0);                       // waits h0 loads; compute overlaps h1 issue below
    LOADH(t, 1);                     // ...actually issue h1 FIRST use next line
    STAGEH(1);                       // waits h1 loads (sibling block covers stall)
    if (r + 1 < ROWS) LOADH(t + 1, 0);   // next row h0 flies through GATHER
    // reduce row sum across waves
    float ls = psum;
#pragma unroll
    for (int d = 1; d < 64; d <<= 1) ls += __shfl_xor(ls, d);
    if ((tid & 63) == 0) red[tid >> 6] = ls;
    if (tid == TAILH - 1) red[8] = blankv;    // scaled blank logit (f32 exact)
    WG_BARRIER();                    // A + red ready
    GATHER(t);
    WG_BARRIER();                    // gathers done before next STAGE overwrites A
  }

#pragma unroll
  for (int k = 0; k < CPT; ++k) {
    float L = (s[k] > 0.f) ? flog2(s[k]) * LN2 : NEGBIG;    // nats
    Lws[(long)q*NB + k*BLOCK + tid] = L;
  }
  if (tid == 0) Sblank[q] = Blocal2 * LN2;
}

#define K3_BLOCK 512

// K3: 512-thread block-scan of the 500 chunk blank-sums -> base offsets
// (inclusive-scan tail gives base[500] = gb[T-1] automatically), then
// per-candidate logsumexp over 500 chunk partials (8-way part split),
// EOS override. Grid 256 x 64 candidates.
__global__ __launch_bounds__(K3_BLOCK)
void ctc_k3(const float* __restrict__ Lws, const float* __restrict__ Sblank,
            const int* __restrict__ cidx, float* __restrict__ out, int nchunk)
{
  __shared__ float base[K3_BLOCK + 1];
  __shared__ float wsum[8];
  __shared__ float pm[8][64], pv[8][64];
  const int tid = threadIdx.x;

  float orig = (tid < nchunk) ? Sblank[tid] : 0.f;
  float x = orig;
#pragma unroll
  for (int d = 1; d < 64; d <<= 1) {
    float y = __shfl_up(x, d);
    if ((tid & 63) >= d) x += y;
  }
  if ((tid & 63) == 63) wsum[tid >> 6] = x;
  __syncthreads();
  {
    const int w = tid >> 6;
    float pre = 0.f;
    for (int k = 0; k < w; ++k) pre += wsum[k];
    x += pre;
  }
  base[tid] = x - orig;   // exclusive prefix; for tid>=nchunk this equals total
  __syncthreads();

  const int c = tid & 63;          // candidate lane
  const int p = tid >> 6;          // part 0..7
  const int i = blockIdx.x * 64 + c;
  const int c0 = p * 63;           // 8*63 = 504 >= 500
  int c1 = c0 + 63; if (c1 > nchunk) c1 = nchunk;

  float mm = NEGBIG, ss = 0.f;
  for (int q2 = c0; q2 < c1; ++q2) {
    float L = Lws[(long)q2*NB + i] + base[q2];
    float nm = fmaxf(mm, L);
    ss = ss*__expf(mm - nm) + __expf(L - nm);
    mm = nm;
  }
  pm[p][c] = mm; pv[p][c] = ss;
  __syncthreads();
  if (p == 0) {
#pragma unroll
    for (int pp = 1; pp < 8; ++pp) {
      float om = pm[pp][c], os = pv[pp][c];
      float nm = fmaxf(mm, om);
      ss = ss*__expf(mm - nm) + os*__expf(om - nm);
      mm = nm;
    }
    float sc = mm + __logf(ss);
    out[i] = (cidx[i] == EOS_ID) ? base[nchunk] : sc;
  }
}

extern "C" void kernel_launch(void* const* d_in, const int* in_sizes, int n_in,
                              void* d_out, int out_size, void* d_ws, size_t ws_size,
                              hipStream_t stream)
{
  const float* P    = (const float*)d_in[0];
  const int*   cidx = (const int*)d_in[2];
  float*       out  = (float*)d_out;

  float* Lws    = (float*)d_ws;                 // 500*16384*4 = 32.8 MB
  float* Sblank = Lws + (long)NCHUNK * NB;      // 2 KB

  ctc_k1<<<dim3(NCHUNK), dim3(BLOCK), 0, stream>>>(P, cidx, Lws, Sblank);
  ctc_k3<<<dim3(NB / 64), dim3(K3_BLOCK), 0, stream>>>(Lws, Sblank, cidx, out, NCHUNK);
}

// Round 13
// 53.919 us; speedup vs baseline: 1.2359x; 1.2359x over previous
//
#include <hip/hip_runtime.h>
#include <hip/hip_fp16.h>

#define T_DIM   1500
#define V4      8000               // float4 per row
#define START_T 9                  // max(U-1,1), U=10
#define NB      16384              // N * ctc_beam
#define BLOCK   896                // 14 waves: 6 producers + 8 consumers
#define NPROD   6
#define NCONS   8
#define ROWS    6                  // 250*6 = 1500 exactly
#define NCHUNK  250
#define NEGBIG  -3.0e38f
#define EOS_ID  1
#define LN2     0.69314718055994531f
#define L2E     1.44269504088896341f
#define SENT_U  0x7FC00000u        // NaN bit pattern: lse2 is never NaN

#if __has_builtin(__builtin_amdgcn_exp2f)
__device__ __forceinline__ float fexp2(float x) { return __builtin_amdgcn_exp2f(x); }
#else
__device__ __forceinline__ float fexp2(float x) { return __expf(x * LN2); }
#endif
#if __has_builtin(__builtin_amdgcn_logf)
__device__ __forceinline__ float flog2(float x) { return __builtin_amdgcn_logf(x); }
#else
__device__ __forceinline__ float flog2(float x) { return __logf(x) * L2E; }
#endif

struct alignas(8) H4 { __half2 a, b; };

// K1, wave-specialized (NO block-wide barriers in the main flow):
//   waves 0-5  = producers: wave p streams row t0+p (128 KB) via 2-deep
//                register batches (8 float4 each), converts to fp16
//                probabilities px = exp2(logit*L2E) into a 2-slot LDS row
//                ring, computes its row's LSE with an in-wave butterfly,
//                then publishes {blank, lse2} via LDS flags (lse2 doubles
//                as the ready flag, NaN sentinel).
//   waves 6-13 = consumers: wave cw owns 2048 candidates; for each row in
//                order: spin on the flag, gather 32 px/lane with a single
//                fma (wave-uniform scale 2^(Blocal2-lse2)), bump the
//                consumed counter so the slot can be reused.
// Producers issue loads BEFORE spinning on slot-free, so HBM requests are
// in flight continuously; compute overlaps streaming across waves.
__global__ __launch_bounds__(BLOCK, 4)   // forces VGPR <= 128 (14 waves/CU)
void ctc_k1(const float* __restrict__ P, const int* __restrict__ cidx,
            float* __restrict__ Lws, float* __restrict__ Sblank)
{
  __shared__ __align__(16) __half A[2][32000];   // 2-slot fp16 px ring (128000 B)
  __shared__ float flagsL[8];                    // lse2 per row (SENT = not ready)
  __shared__ float flagsB[8];                    // scaled blank logit per row
  __shared__ int   cons[8];                      // consumed counters per row
  const int tid = threadIdx.x;
  const int w   = tid >> 6;
  const int l   = tid & 63;
  const int q   = blockIdx.x;
  const int t0  = q * ROWS;

  if (tid < ROWS) { ((unsigned*)flagsL)[tid] = SENT_U; cons[tid] = 0; }
  __syncthreads();   // the only block-wide barrier

  if (w < NPROD) {
    // ---------------- producer: row p = w ----------------
    const int p = w;
    const float4* rp = (const float4*)P + (long)(t0 + p) * V4;
    __half* Arow = A[p & 1];
    float4 va[8], vb[8];
    float psum = 0.f, blankv = 0.f;

    // batch b covers float4 indices l + 64*(8b+k), k<cnt; 16 batches, last=5
    auto LOADB = [&](float4 (&v)[8], int b) {
      const int cnt = (b == 15) ? 5 : 8;
#pragma unroll
      for (int k = 0; k < 8; ++k) if (k < cnt) v[k] = rp[l + 64*(8*b + k)];
    };
    auto CONV = [&](float4 (&v)[8], int b) {
      const int cnt = (b == 15) ? 5 : 8;
#pragma unroll
      for (int k = 0; k < 8; ++k) if (k < cnt) {
        float p0 = fexp2(v[k].x * L2E), p1 = fexp2(v[k].y * L2E);
        float p2 = fexp2(v[k].z * L2E), p3 = fexp2(v[k].w * L2E);
        psum += (p0 + p1) + (p2 + p3);
        H4 h; h.a = __floats2half2_rn(p0, p1); h.b = __floats2half2_rn(p2, p3);
        ((H4*)Arow)[l + 64*(8*b + k)] = h;
        if (b == 15 && k == 4 && l == 63) blankv = v[k].w * L2E;  // elem 31999
      }
    };

    LOADB(va, 0); LOADB(vb, 1);          // loads in flight BEFORE the spin
    if (p >= 2) {
      volatile int* cv = cons;
      while (cv[p - 2] < NCONS) __builtin_amdgcn_s_sleep(2);
      asm volatile("" ::: "memory");     // no px writes hoisted above the spin
    }
#pragma unroll
    for (int b = 0; b < 16; b += 2) {
      CONV(va, b);
      if (b + 2 < 16) LOADB(va, b + 2);
      CONV(vb, b + 1);
      if (b + 3 < 16) LOADB(vb, b + 3);
    }
#pragma unroll
    for (int d = 1; d < 64; d <<= 1) psum += __shfl_xor(psum, d);
    if (l == 63) flagsB[p] = blankv;
    asm volatile("s_waitcnt lgkmcnt(0)" ::: "memory");  // px + blank visible first
    if (l == 0) flagsL[p] = flog2(psum);                // publish (ready flag)
  } else {
    // ---------------- consumer: candidates cw*2048 .. +2047 ----------------
    const int cw = w - NPROD;
    unsigned cidp[16];
    float s[32];
#pragma unroll
    for (int j = 0; j < 16; ++j) {
      unsigned c0 = (unsigned)cidx[cw*2048 + (2*j  )*64 + l] * 2u;
      unsigned c1 = (unsigned)cidx[cw*2048 + (2*j+1)*64 + l] * 2u;
      cidp[j] = c0 | (c1 << 16);
      s[2*j] = 0.f; s[2*j+1] = 0.f;
    }
    float Bl2 = 0.f;
    volatile unsigned* fl = (volatile unsigned*)flagsL;
    volatile float*    fb = (volatile float*)flagsB;
    for (int r = 0; r < ROWS; ++r) {
      while (fl[r] == SENT_U) __builtin_amdgcn_s_sleep(2);
      asm volatile("" ::: "memory");     // gathers not hoisted above the spin
      const float lse2 = __uint_as_float(fl[r]);
      const float b2   = fb[r];
      if (t0 + r >= START_T) {
        const float sc = fexp2(Bl2 - lse2);   // wave-uniform scale
        const char* rb = (const char*)A[r & 1];
#pragma unroll
        for (int j = 0; j < 16; ++j) {
          unsigned pk = cidp[j];
          float p0 = __half2float(*(const __half*)(rb + (pk & 0xffffu)));
          float p1 = __half2float(*(const __half*)(rb + (pk >> 16)));
          s[2*j]   = fmaf(sc, p0, s[2*j]);
          s[2*j+1] = fmaf(sc, p1, s[2*j+1]);
        }
      }
      Bl2 += b2 - lse2;
      asm volatile("" ::: "memory");     // gathers done before marking consumed
      if (l == 0) atomicAdd(&cons[r], 1);
    }
#pragma unroll
    for (int k = 0; k < 32; ++k) {
      float L = (s[k] > 0.f) ? flog2(s[k]) * LN2 : NEGBIG;   // nats
      Lws[(long)q*NB + cw*2048 + k*64 + l] = L;
    }
    if (cw == 0 && l == 0) Sblank[q] = Bl2 * LN2;
  }
}

#define K3_BLOCK 256
#define K3_CPB   128

// K3: block-scan chunk blank-sums -> base offsets, per-candidate logsumexp
// over the 250 chunk partials (2-way chunk split), EOS override.
__global__ __launch_bounds__(K3_BLOCK)
void ctc_k3(const float* __restrict__ Lws, const float* __restrict__ Sblank,
            const int* __restrict__ cidx, float* __restrict__ out, int nchunk)
{
  __shared__ float base[258];
  __shared__ float wsum[4];
  __shared__ float redm[K3_BLOCK], reds[K3_BLOCK];
  const int tid = threadIdx.x;

  float orig = (tid < nchunk) ? Sblank[tid] : 0.f;
  float x = orig;
#pragma unroll
  for (int d = 1; d < 64; d <<= 1) {
    float y = __shfl_up(x, d);
    if ((tid & 63) >= d) x += y;
  }
  if ((tid & 63) == 63) wsum[tid >> 6] = x;
  __syncthreads();
  {
    const int w = tid >> 6;
    float pre = 0.f;
    if (w > 0) pre += wsum[0];
    if (w > 1) pre += wsum[1];
    if (w > 2) pre += wsum[2];
    x += pre;
  }
  if (tid < nchunk)      base[tid] = x - orig;   // exclusive prefix
  if (tid == nchunk - 1) base[nchunk] = x;       // total = gb[T-1]
  __syncthreads();

  const int half = tid >> 7;
  const int cl   = tid & 127;
  const int i    = blockIdx.x * K3_CPB + cl;
  const int hl   = (nchunk + 1) >> 1;
  const int c0   = half * hl;
  int c1 = c0 + hl; if (c1 > nchunk) c1 = nchunk;

  float mm = NEGBIG, ss = 0.f;
#pragma unroll 4
  for (int q2 = c0; q2 < c1; ++q2) {
    float L = Lws[(long)q2*NB + i] + base[q2];
    float nm = fmaxf(mm, L);
    ss = ss*__expf(mm - nm) + __expf(L - nm);
    mm = nm;
  }
  redm[tid] = mm; reds[tid] = ss;
  __syncthreads();
  if (half == 0) {
    float om = redm[tid + 128], os = reds[tid + 128];
    float nm = fmaxf(mm, om);
    ss = ss*__expf(mm - nm) + os*__expf(om - nm);
    mm = nm;
    float sc = mm + __logf(ss);
    out[i] = (cidx[i] == EOS_ID) ? base[nchunk] : sc;
  }
}

extern "C" void kernel_launch(void* const* d_in, const int* in_sizes, int n_in,
                              void* d_out, int out_size, void* d_ws, size_t ws_size,
                              hipStream_t stream)
{
  const float* P    = (const float*)d_in[0];
  const int*   cidx = (const int*)d_in[2];
  float*       out  = (float*)d_out;

  float* Lws    = (float*)d_ws;                 // 16.4 MB
  float* Sblank = Lws + (long)NCHUNK * NB;      // 1 KB

  ctc_k1<<<dim3(NCHUNK), dim3(BLOCK), 0, stream>>>(P, cidx, Lws, Sblank);
  ctc_k3<<<dim3(NB / K3_CPB), dim3(K3_BLOCK), 0, stream>>>(Lws, Sblank, cidx, out, NCHUNK);
}

// Round 14
// 52.008 us; speedup vs baseline: 1.2813x; 1.0367x over previous
//
#include <hip/hip_runtime.h>
#include <hip/hip_fp16.h>

#define T_DIM   1500
#define V4      8000               // float4 per row
#define START_T 9                  // max(U-1,1), U=10
#define NB      16384              // N * ctc_beam
#define BLOCK   896                // 14 waves: 6 producers + 8 consumers
#define NPROD   6
#define NCONS   8
#define RING    4                  // fp8 rows: 4 x 32000 B = 128000 B
#define ROWS    6                  // 250*6 = 1500 exactly
#define NCHUNK  250
#define NEGBIG  -3.0e38f
#define EOS_ID  1
#define LN2     0.69314718055994531f
#define L2E     1.44269504088896341f
#define SENT_U  0x7FC00000u        // NaN bit pattern: lse2 is never NaN

#if __has_builtin(__builtin_amdgcn_exp2f)
__device__ __forceinline__ float fexp2(float x) { return __builtin_amdgcn_exp2f(x); }
#else
__device__ __forceinline__ float fexp2(float x) { return __expf(x * LN2); }
#endif
#if __has_builtin(__builtin_amdgcn_logf)
__device__ __forceinline__ float flog2(float x) { return __builtin_amdgcn_logf(x); }
#else
__device__ __forceinline__ float flog2(float x) { return __logf(x) * L2E; }
#endif

// ---- fp8 e4m3 pack/unpack (HW cvt if present, manual fallback) ----
__device__ __forceinline__ unsigned fp8enc1(float p) {
  unsigned u = __float_as_uint(p);
  int v = (int)((u + 0x80000u) >> 20) - 0x3C0;
  v = v < 1 ? 0 : (v > 126 ? 126 : v);
  return (unsigned)v;
}
__device__ __forceinline__ unsigned fp8pack4(float p0, float p1, float p2, float p3) {
#if __has_builtin(__builtin_amdgcn_cvt_pk_fp8_f32)
  int w = 0;
  w = __builtin_amdgcn_cvt_pk_fp8_f32(p0, p1, w, false);
  w = __builtin_amdgcn_cvt_pk_fp8_f32(p2, p3, w, true);
  return (unsigned)w;
#else
  return fp8enc1(p0) | (fp8enc1(p1) << 8) | (fp8enc1(p2) << 16) | (fp8enc1(p3) << 24);
#endif
}
__device__ __forceinline__ float fp8dec(unsigned b) {
#if __has_builtin(__builtin_amdgcn_cvt_f32_fp8)
  return __builtin_amdgcn_cvt_f32_fp8((int)b, 0);
#else
  return b ? __uint_as_float((b + 0x3C0u) << 20) : 0.f;   // subnormals approx; negligible
#endif
}

// K1, wave-specialized with a 4-deep fp8 row ring (NO block barriers in the
// main flow). Producers 0-5: wave p streams row t0+p (128 KB) via 2-deep
// 8xfloat4 register batches, converts to fp8 px = exp2(logit*L2E) into ring
// slot p&3, computes the row LSE in-wave, publishes {lse2, blank2} via LDS
// flags. Ring-4 => 4 producers stream CONCURRENTLY from t=0 (~40-60 KB HBM
// in flight per CU continuously; the 9.2 KB BW*latency product is covered
// through every handoff). Consumers 6-13: 2048 candidates each; per row:
// spin, gather px (ds_read_u8 + fp8 decode), one fma each with wave-uniform
// scale 2^(Blocal2 - lse2), bump consumed counter.
__global__ __launch_bounds__(BLOCK, 4)   // 128-VGPR cap; both roles fit (~90)
void ctc_k1(const float* __restrict__ P, const int* __restrict__ cidx,
            float* __restrict__ Lws, float* __restrict__ Sblank)
{
  __shared__ __align__(16) unsigned A[RING][V4];   // 4 x 32000B fp8 px rows
  __shared__ float flagsL[8];                      // lse2 per row (SENT=not ready)
  __shared__ float flagsB[8];                      // scaled blank logit per row
  __shared__ int   cons[8];                        // consumed counters per row
  const int tid = threadIdx.x;
  const int w   = tid >> 6;
  const int l   = tid & 63;
  const int q   = blockIdx.x;
  const int t0  = q * ROWS;

  if (tid < ROWS) { ((unsigned*)flagsL)[tid] = SENT_U; cons[tid] = 0; }
  __syncthreads();   // the only block-wide barrier

  if (w < NPROD) {
    // ---------------- producer: row p = w, ring slot p&3 ----------------
    const int p = w;
    const float4* rp = (const float4*)P + (long)(t0 + p) * V4;
    unsigned* Arow = A[p & 3];
    float4 va[8], vb[8];
    float psum = 0.f, blankv = 0.f;

    // batch b covers float4 indices l + 64*(8b+k), k<cnt; 16 batches, last=5
    auto LOADB = [&](float4 (&v)[8], int b) {
      const int cnt = (b == 15) ? 5 : 8;
#pragma unroll
      for (int k = 0; k < 8; ++k) if (k < cnt) v[k] = rp[l + 64*(8*b + k)];
    };
    auto CONV = [&](float4 (&v)[8], int b) {
      const int cnt = (b == 15) ? 5 : 8;
#pragma unroll
      for (int k = 0; k < 8; ++k) if (k < cnt) {
        float p0 = fexp2(v[k].x * L2E), p1 = fexp2(v[k].y * L2E);
        float p2 = fexp2(v[k].z * L2E), p3 = fexp2(v[k].w * L2E);
        psum += (p0 + p1) + (p2 + p3);                 // exact f32 row sum
        Arow[l + 64*(8*b + k)] = fp8pack4(p0, p1, p2, p3);
        if (b == 15 && k == 4 && l == 63) blankv = v[k].w * L2E;  // elem 31999
      }
    };

    LOADB(va, 0); LOADB(vb, 1);          // loads in flight BEFORE any spin
    if (p >= RING) {
      volatile int* cv = cons;
      while (cv[p - RING] < NCONS) __builtin_amdgcn_s_sleep(2);
      asm volatile("" ::: "memory");     // no px writes hoisted above the spin
    }
#pragma unroll
    for (int b = 0; b < 16; b += 2) {
      CONV(va, b);
      if (b + 2 < 16) LOADB(va, b + 2);
      CONV(vb, b + 1);
      if (b + 3 < 16) LOADB(vb, b + 3);
    }
#pragma unroll
    for (int d = 1; d < 64; d <<= 1) psum += __shfl_xor(psum, d);
    if (l == 63) flagsB[p] = blankv;
    asm volatile("s_waitcnt lgkmcnt(0)" ::: "memory");  // px + blank visible first
    if (l == 0) flagsL[p] = flog2(psum);                // publish (ready flag)
  } else {
    // ---------------- consumer: candidates cw*2048 .. +2047 ----------------
    const int cw = w - NPROD;
    unsigned cidp[16];                   // two u16 byte-offsets per VGPR (c < 32000)
    float s[32];
#pragma unroll
    for (int j = 0; j < 16; ++j) {
      unsigned c0 = (unsigned)cidx[cw*2048 + (2*j  )*64 + l];
      unsigned c1 = (unsigned)cidx[cw*2048 + (2*j+1)*64 + l];
      cidp[j] = c0 | (c1 << 16);
      s[2*j] = 0.f; s[2*j+1] = 0.f;
    }
    float Bl2 = 0.f;
    volatile unsigned* fl = (volatile unsigned*)flagsL;
    volatile float*    fb = (volatile float*)flagsB;
    for (int r = 0; r < ROWS; ++r) {
      while (fl[r] == SENT_U) __builtin_amdgcn_s_sleep(2);
      asm volatile("" ::: "memory");     // gathers not hoisted above the spin
      const float lse2 = __uint_as_float(fl[r]);
      const float b2   = fb[r];
      if (t0 + r >= START_T) {
        const float sc = fexp2(Bl2 - lse2);   // wave-uniform scale
        const unsigned char* rb = (const unsigned char*)A[r & 3];
#pragma unroll
        for (int j = 0; j < 16; ++j) {
          unsigned pk = cidp[j];
          float p0 = fp8dec(rb[pk & 0xffffu]);
          float p1 = fp8dec(rb[pk >> 16]);
          s[2*j]   = fmaf(sc, p0, s[2*j]);
          s[2*j+1] = fmaf(sc, p1, s[2*j+1]);
        }
      }
      Bl2 += b2 - lse2;
      asm volatile("" ::: "memory");     // gathers done before marking consumed
      if (l == 0) atomicAdd(&cons[r], 1);
    }
#pragma unroll
    for (int k = 0; k < 32; ++k) {
      float L = (s[k] > 0.f) ? flog2(s[k]) * LN2 : NEGBIG;   // nats
      Lws[(long)q*NB + cw*2048 + k*64 + l] = L;
    }
    if (cw == 0 && l == 0) Sblank[q] = Bl2 * LN2;
  }
}

#define K3_BLOCK 256
#define K3_CPB   128

// K3: block-scan chunk blank-sums -> base offsets, per-candidate logsumexp
// over the 250 chunk partials (2-way chunk split), EOS override.
__global__ __launch_bounds__(K3_BLOCK)
void ctc_k3(const float* __restrict__ Lws, const float* __restrict__ Sblank,
            const int* __restrict__ cidx, float* __restrict__ out, int nchunk)
{
  __shared__ float base[258];
  __shared__ float wsum[4];
  __shared__ float redm[K3_BLOCK], reds[K3_BLOCK];
  const int tid = threadIdx.x;

  float orig = (tid < nchunk) ? Sblank[tid] : 0.f;
  float x = orig;
#pragma unroll
  for (int d = 1; d < 64; d <<= 1) {
    float y = __shfl_up(x, d);
    if ((tid & 63) >= d) x += y;
  }
  if ((tid & 63) == 63) wsum[tid >> 6] = x;
  __syncthreads();
  {
    const int w = tid >> 6;
    float pre = 0.f;
    if (w > 0) pre += wsum[0];
    if (w > 1) pre += wsum[1];
    if (w > 2) pre += wsum[2];
    x += pre;
  }
  if (tid < nchunk)      base[tid] = x - orig;   // exclusive prefix
  if (tid == nchunk - 1) base[nchunk] = x;       // total = gb[T-1]
  __syncthreads();

  const int half = tid >> 7;
  const int cl   = tid & 127;
  const int i    = blockIdx.x * K3_CPB + cl;
  const int hl   = (nchunk + 1) >> 1;
  const int c0   = half * hl;
  int c1 = c0 + hl; if (c1 > nchunk) c1 = nchunk;

  float mm = NEGBIG, ss = 0.f;
#pragma unroll 4
  for (int q2 = c0; q2 < c1; ++q2) {
    float L = Lws[(long)q2*NB + i] + base[q2];
    float nm = fmaxf(mm, L);
    ss = ss*__expf(mm - nm) + __expf(L - nm);
    mm = nm;
  }
  redm[tid] = mm; reds[tid] = ss;
  __syncthreads();
  if (half == 0) {
    float om = redm[tid + 128], os = reds[tid + 128];
    float nm = fmaxf(mm, om);
    ss = ss*__expf(mm - nm) + os*__expf(om - nm);
    mm = nm;
    float sc = mm + __logf(ss);
    out[i] = (cidx[i] == EOS_ID) ? base[nchunk] : sc;
  }
}

extern "C" void kernel_launch(void* const* d_in, const int* in_sizes, int n_in,
                              void* d_out, int out_size, void* d_ws, size_t ws_size,
                              hipStream_t stream)
{
  const float* P    = (const float*)d_in[0];
  const int*   cidx = (const int*)d_in[2];
  float*       out  = (float*)d_out;

  float* Lws    = (float*)d_ws;                 // 16.4 MB
  float* Sblank = Lws + (long)NCHUNK * NB;      // 1 KB

  ctc_k1<<<dim3(NCHUNK), dim3(BLOCK), 0, stream>>>(P, cidx, Lws, Sblank);
  ctc_k3<<<dim3(NB / K3_CPB), dim3(K3_BLOCK), 0, stream>>>(Lws, Sblank, cidx, out, NCHUNK);
}